// Round 5
// baseline (175.701 us; speedup 1.0000x reference)
//
#include <hip/hip_runtime.h>

typedef unsigned int  u32;
typedef unsigned short u16;

typedef float    f4  __attribute__((ext_vector_type(4)));
typedef short    bf8 __attribute__((ext_vector_type(8)));
typedef __fp16   h8  __attribute__((ext_vector_type(8)));
typedef __fp16   h2  __attribute__((ext_vector_type(2)));

#define NBLK  512
#define ITERS 8      // 512 blocks * 8 iters * 64 boards = 262144
#define ZSTR  104    // z1 row stride (u16); 52 dw/row; 16B-aligned rows (b128)

// ---- workspace layout (bytes); total 59280 ----
#define WS_AF   0        // u16[16*3*512]   = 49152 B : W1 bf16, K+M-permuted, lane-ordered (T=w*4+tt)
#define WS_OW   49152    // u32[8*64*4]     =  8192 B : out_w fp16-pair A-frags, lane-ordered (c'=w*2+c)
#define WS_TAB  57344    // uint2[242]      =  1936 B : Th[0..120], Tv[121..241]

// fp32 -> bf16 bits, round-half-up (weights only; ties are measure-zero)
__device__ __forceinline__ u32 bfr(float f) {
    union { float f; u32 u; } v; v.f = f;
    return (v.u + 0x8000u) >> 16;
}
__device__ __forceinline__ u32 pk2(float lo, float hi) { return bfr(lo) | (bfr(hi) << 16); }
__device__ __forceinline__ u32 pkh(float lo, float hi) {   // fp16 pair (RTZ, 1 inst)
    union { h2 h; u32 u; } v; v.h = __builtin_amdgcn_cvt_pkrtz(lo, hi); return v.u;
}
// packed fp16 relu: one v_pk_max_f16 against 0 (inline asm; ROCm 7.2 __hmax2 header is broken)
__device__ __forceinline__ u32 pkmax0(u32 x) {
    u32 r; asm("v_pk_max_f16 %0, %1, %2" : "=v"(r) : "v"(x), "v"(0u)); return r;
}
__device__ __forceinline__ u32 nrev(u32 x) {
    return ((x >> 12) & 0xFu) | ((x >> 4) & 0xF0u) | ((x << 4) & 0xF00u) | ((x << 12) & 0xF000u);
}

// ======================= prep kernel: per-LAUNCH weight transform (UNCHANGED) =======================
__launch_bounds__(256)
__global__ void smartcnn_prep(const float* __restrict__ c0w, const float* __restrict__ c0b,
                              const float* __restrict__ c1w,
                              const float* __restrict__ lw,  const float* __restrict__ ow,
                              u16* __restrict__ wsAf, u32* __restrict__ wsOw,
                              uint2* __restrict__ wsTab)
{
    const int i = blockIdx.x * 256 + threadIdx.x;
    if (i < 24576) {
        // af element: i = (T*3+s)*512 + (qd*16+m)*8 + j, T = w*4+tt
        const int j    = i & 7;
        const int lane = (i >> 3) & 63;
        const int rest = i >> 9;
        const int m  = lane & 15, qd = lane >> 4;
        const int s  = rest % 3;
        const int wtt = rest / 3;
        const int tt = wtt & 3, w = wtt >> 2;
        const int tbase = ((tt & 1) ? 4 : 0) + ((tt >> 1) ? 32 : 0);
        const int fid = 64*w + tbase + 8*(m >> 2) + (m & 3);        // M-permuted feature row
        const int kp = s*32 + qd*8 + j;                              // fragment K position
        const int kq = (kp < 48) ? kp : kp - 48;                     // invert K-permutation:
        const int ko = ((kp < 48) ? 0 : 48) + (kq & 3)*12 + (kq >> 2); // kp=(ko%12)*4+ko/12
        wsAf[i] = (u16)bfr(lw[fid*96 + ko]);
    } else if (i < 26624) {
        // out_w fp16-pair element: t = (c'*64 + qd*16+m)*4 + k, c' = w*2+c
        const int t = i - 24576;
        const int k    = t & 3;
        const int lane = (t >> 2) & 63;
        const int wc   = t >> 8;
        const int m = lane & 15, qd = lane >> 4;
        const int c = wc & 1, w = wc >> 1;
        u32 val = 0u;
        if (m < 4) {   // rows 0-3 = actions, rows 4-15 = 0
            const int n8 = 64*w + 32*c + qd*8;
            val = pkh(ow[m*256 + n8 + 2*k], ow[m*256 + n8 + 2*k + 1]);
        }
        wsOw[t] = val;
    } else if (i < 26866) {
        // conv pair tables: t<121 -> Th (conv0 pair + bias), else Tv (conv1 pair)
        const int t = i - 26624;
        const int e = (t < 121) ? t : t - 121;
        const int v1 = e / 11, v2 = e - v1*11;
        float a[4];
        #pragma unroll
        for (int c = 0; c < 4; ++c) {
            if (t < 121)
                a[c] = fmaxf(c0w[c*24 + 0] + c0w[c*24 + (1+v1)*2 + 0] + c0b[c]
                           + c0w[c*24 + 1] + c0w[c*24 + (1+v2)*2 + 1], 0.f);
            else
                a[c] = fmaxf(c1w[c*24 + 0] + c1w[c*24 + (1+v1)*2 + 0]
                           + c1w[c*24 + 1] + c1w[c*24 + (1+v2)*2 + 1], 0.f);
        }
        wsTab[t] = make_uint2(pk2(a[0], a[1]), pk2(a[2], a[3]));
    }
}

// ======================= main kernel: barrier-free per-wave pipeline =======================
// R4 post-mortem: old structure was ~90% stalled on per-iteration __syncthreads convoys
// (cross-wave z1 + Pb reduction forced 6 barriers/block; all 4 blocks/CU in near-lockstep).
// New: each wave owns 16 boards end-to-end (all 256 features, both GEMMs, softmax).
// W1 streams from a block-shared LDS copy; Pb/flg/z1-double-buffer deleted; ZERO barriers
// after setup. Cost: 2 blocks/CU (64.4KB LDS) -> 2 waves/SIMD; regs ~210 peak < 256 cap.
__launch_bounds__(256, 2)
__global__ void smartcnn_fused(const int* __restrict__ exps,
                               const float* __restrict__ lb, const float* __restrict__ ob,
                               const u16* __restrict__ wsAf, const u32* __restrict__ wsOw,
                               const uint2* __restrict__ wsTab,
                               float* __restrict__ out)
{
    __shared__ u16   afL[48 * 512];      // 49152 B : all 48 W1 fragments, lane-ordered
    __shared__ uint2 ThA[121];           // conv0 pair table (bf16 x4 channels)
    __shared__ uint2 TvA[121];           // conv1 pair table
    __shared__ u16   z1[64 * ZSTR];      // 13312 B : 16 rows per wave, wave-private region

    const int tid  = threadIdx.x;
    const int w    = tid >> 6;
    const int lane = tid & 63;
    const int m    = lane & 15;
    const int qd   = lane >> 4;

    // ---- tables ----
    if (tid < 242) {
        uint2 v = wsTab[tid];
        if (tid < 121) ThA[tid] = v; else TvA[tid - 121] = v;
    }
    // ---- stage all 48 af fragments into LDS (12 per wave, coalesced b128 copies) ----
    #pragma unroll
    for (int f2 = 0; f2 < 12; ++f2) {
        const int f = w * 12 + f2;
        uint4 t = *(const uint4*)((const char*)wsAf + f * 1024 + lane * 16);
        *(uint4*)((char*)afL + f * 1024 + lane * 16) = t;
    }
    // ---- out_w A-frags, all 8 K-blocks (32 VGPR) ----
    u32 owA[8][4];
    #pragma unroll
    for (int c = 0; c < 8; ++c) {
        uint4 t = *(const uint4*)(wsOw + c * 256 + lane * 4);
        owA[c][0] = t.x; owA[c][1] = t.y; owA[c][2] = t.z; owA[c][3] = t.w;
    }
    // ---- linear_b, all 16 tiles (64 VGPR): lbT[T][j] = lb[tbase16(T) + 8qd + j] ----
    f4 lbT[16];
    #pragma unroll
    for (int T = 0; T < 16; ++T) {
        const int tbase = ((T & 1) ? 4 : 0) + ((T >> 1) * 32);
        lbT[T] = *(const f4*)(lb + tbase + 8 * qd);
    }
    const float4 obv = *(const float4*)ob;

    const int bb = blockIdx.x * (ITERS * 64);
    __syncthreads();   // the ONLY barrier: afL + tables published

    int4 e4 = *(const int4*)(exps + (size_t)(bb + w*16 + m)*16 + qd*4);

    #pragma unroll 1
    for (int it = 0; it < ITERS; ++it) {
        // ---------- phase 1: flips + z1 row build (wave-private; fv/fh stay in registers) ----------
        u32 pkd = (u32)e4.x | ((u32)e4.y << 4) | ((u32)e4.z << 8) | ((u32)e4.w << 12);
        // prefetch next iteration's exps immediately (clamped; in flight across whole iteration)
        const int itn = (it + 1 < ITERS) ? it + 1 : it;
        int4 e4n = *(const int4*)(exps + (size_t)(bb + itn*64 + w*16 + m)*16 + qd*4);

        u32 R0 = (u32)__shfl((int)pkd, m);
        u32 R1 = (u32)__shfl((int)pkd, m + 16);
        u32 R2 = (u32)__shfl((int)pkd, m + 32);
        u32 R3 = (u32)__shfl((int)pkd, m + 48);
        u32 c0v = R0 & 15u, c1v = (R0 >> 12) & 15u, c2v = R3 & 15u, c3v = (R3 >> 12) & 15u;
        u32 best = c0v; int ix = 0;
        if (c1v > best) { best = c1v; ix = 1; }
        if (c2v > best) { best = c2v; ix = 2; }
        if (c3v > best) { best = c3v; ix = 3; }
        const bool fv = (ix >= 2), fh = ((ix & 1) != 0);
        u32 F0 = fv ? R3 : R0;
        u32 F1 = fv ? R2 : R1;
        u32 F2 = fv ? R1 : R2;
        u32 F3 = fv ? R0 : R3;
        if (fh) { F0 = nrev(F0); F1 = nrev(F1); F2 = nrev(F2); F3 = nrev(F3); }

        const u32 Fq = (qd == 0) ? F0 : (qd == 1) ? F1 : (qd == 2) ? F2 : F3;
        u32 nbq0 = Fq & 15u, nbq1 = (Fq >> 4) & 15u, nbq2 = (Fq >> 8) & 15u, nbq3 = (Fq >> 12) & 15u;
        u32 nbc0 = (F0 >> (4*qd)) & 15u, nbc1 = (F1 >> (4*qd)) & 15u;
        u32 nbc2 = (F2 >> (4*qd)) & 15u, nbc3 = (F3 >> (4*qd)) & 15u;

        uint2 H0 = ThA[nbq0*11u + nbq1];
        uint2 H1 = ThA[nbq1*11u + nbq2];
        uint2 H2 = ThA[nbq2*11u + nbq3];
        uint2 V0 = TvA[nbc0*11u + nbc1];
        uint2 V1 = TvA[nbc1*11u + nbc2];
        uint2 V2 = TvA[nbc2*11u + nbc3];

        u16* zrow = &z1[(w*16 + m) * ZSTR];
        *(uint2*)(zrow + (qd*3 + 0)*4) = H0;
        *(uint2*)(zrow + (qd*3 + 1)*4) = H1;
        *(uint2*)(zrow + (qd*3 + 2)*4) = H2;
        *(uint2*)(zrow + 48 + (0*4 + qd)*4) = V0;
        *(uint2*)(zrow + 48 + (1*4 + qd)*4) = V1;
        *(uint2*)(zrow + 48 + (2*4 + qd)*4) = V2;

        // ---------- GEMM1: z1[16x96] x W1^T -> all 256 features, 16 tiles x K=96 ----------
        // zb: this wave's own z1 rows (same-wave DS ordering guarantees visibility)
        const u16* zbase = &z1[(w*16 + m) * ZSTR + qd*8];
        bf8 zb0 = *(const bf8*)(zbase);
        bf8 zb1 = *(const bf8*)(zbase + 32);
        bf8 zb2 = *(const bf8*)(zbase + 64);

        __builtin_amdgcn_s_setprio(1);
        f4 acc[16];
        #pragma unroll
        for (int T = 0; T < 16; ++T) {
            const u16* ap = &afL[(T*3) * 512 + lane * 8];
            bf8 a0 = *(const bf8*)(ap);
            bf8 a1 = *(const bf8*)(ap + 512);
            bf8 a2 = *(const bf8*)(ap + 1024);
            f4 a = __builtin_amdgcn_mfma_f32_16x16x32_bf16(a0, zb0, lbT[T], 0, 0, 0);
            a     = __builtin_amdgcn_mfma_f32_16x16x32_bf16(a1, zb1, a,      0, 0, 0);
            acc[T] = __builtin_amdgcn_mfma_f32_16x16x32_bf16(a2, zb2, a,     0, 0, 0);
        }

        // ---------- GEMM2: relu/fp16 pack in-lane -> logits, K=256 in 8 blocks, 2 acc chains ----------
        f4 p0 = {0.f, 0.f, 0.f, 0.f}, p1 = {0.f, 0.f, 0.f, 0.f};
        #pragma unroll
        for (int c = 0; c < 8; ++c) {
            union { u32 u[4]; h8 v; } bu, au;
            bu.u[0] = pkmax0(pkh(acc[2*c  ][0], acc[2*c  ][1]));
            bu.u[1] = pkmax0(pkh(acc[2*c  ][2], acc[2*c  ][3]));
            bu.u[2] = pkmax0(pkh(acc[2*c+1][0], acc[2*c+1][1]));
            bu.u[3] = pkmax0(pkh(acc[2*c+1][2], acc[2*c+1][3]));
            au.u[0] = owA[c][0]; au.u[1] = owA[c][1]; au.u[2] = owA[c][2]; au.u[3] = owA[c][3];
            if (c & 1) p1 = __builtin_amdgcn_mfma_f32_16x16x32_f16(au.v, bu.v, p1, 0, 0, 0);
            else       p0 = __builtin_amdgcn_mfma_f32_16x16x32_f16(au.v, bu.v, p0, 0, 0, 0);
        }
        __builtin_amdgcn_s_setprio(0);

        // ---------- epilogue: softmax + flip-permute + store (qd==0 lanes hold action rows) ----------
        if (qd == 0) {
            float L0 = p0[0] + p1[0] + obv.x;
            float L1 = p0[1] + p1[1] + obv.y;
            float L2 = p0[2] + p1[2] + obv.z;
            float L3 = p0[3] + p1[3] + obv.w;
            float mx = fmaxf(fmaxf(L0, L1), fmaxf(L2, L3));
            float e0 = __expf(L0 - mx), e1 = __expf(L1 - mx), e2 = __expf(L2 - mx), e3 = __expf(L3 - mx);
            float inv = __builtin_amdgcn_rcpf(e0 + e1 + e2 + e3);
            float P0 = e0 * inv, P1 = e1 * inv, P2 = e2 * inv, P3 = e3 * inv;
            float4 o;
            o.x = fh ? P1 : P0;
            o.y = fh ? P0 : P1;
            o.z = fv ? P3 : P2;
            o.w = fv ? P2 : P3;
            // NOTE: ref permute: vert flip swaps actions (0,1); horiz swaps (2,3).
            // fv corresponds to row flip -> actions 0/1; fh -> 2/3. (matches old fl bits: fl&1=fv, fl&2=fh)
            o.x = fv ? P1 : P0;
            o.y = fv ? P0 : P1;
            o.z = fh ? P3 : P2;
            o.w = fh ? P2 : P3;
            *(float4*)(out + (size_t)(bb + it*64 + w*16 + m) * 4) = o;
        }
        e4 = e4n;
    }
}

extern "C" void kernel_launch(void* const* d_in, const int* in_sizes, int n_in,
                              void* d_out, int out_size, void* d_ws, size_t ws_size,
                              hipStream_t stream) {
    const int*   exps = (const int*)  d_in[0];
    const float* c0w  = (const float*)d_in[1];
    const float* c0b  = (const float*)d_in[2];
    const float* c1w  = (const float*)d_in[3];
    const float* lw   = (const float*)d_in[4];
    const float* lbv  = (const float*)d_in[5];
    const float* oww  = (const float*)d_in[6];
    const float* obv  = (const float*)d_in[7];
    u16*   wsAf  = (u16*)  ((char*)d_ws + WS_AF);
    u32*   wsOw  = (u32*)  ((char*)d_ws + WS_OW);
    uint2* wsTab = (uint2*)((char*)d_ws + WS_TAB);
    smartcnn_prep<<<105, 256, 0, stream>>>(c0w, c0b, c1w, lw, oww, wsAf, wsOw, wsTab);
    smartcnn_fused<<<NBLK, 256, 0, stream>>>(exps, lbv, obv, wsAf, wsOw, wsTab, (float*)d_out);
}

// Round 7
// 93.452 us; speedup vs baseline: 1.8801x; 1.8801x over previous
//
#include <hip/hip_runtime.h>

typedef unsigned int  u32;
typedef unsigned short u16;

typedef float    f4  __attribute__((ext_vector_type(4)));
typedef short    bf8 __attribute__((ext_vector_type(8)));
typedef __fp16   h8  __attribute__((ext_vector_type(8)));
typedef __fp16   h2  __attribute__((ext_vector_type(2)));

#define NBLK  512    // 512 blocks * 4 waves * 128 boards = 262144
#define ZSTR  104    // z1 row stride (u16); 52 dw/row; 16B-aligned rows (b128)

// ---- workspace layout (bytes); total 59280 ----
#define WS_AF   0        // u16[16*3*512]   = 49152 B : W1 bf16, K+M-permuted, lane-ordered (T=w*4+tt)
#define WS_OW   49152    // u32[8*64*4]     =  8192 B : out_w fp16-pair A-frags, lane-ordered
#define WS_TAB  57344    // uint2[242]      =  1936 B : Th[0..120], Tv[121..241]

// fp32 -> bf16 bits, round-half-up (weights only; ties are measure-zero)
__device__ __forceinline__ u32 bfr(float f) {
    union { float f; u32 u; } v; v.f = f;
    return (v.u + 0x8000u) >> 16;
}
__device__ __forceinline__ u32 pk2(float lo, float hi) { return bfr(lo) | (bfr(hi) << 16); }
__device__ __forceinline__ u32 pkh(float lo, float hi) {   // fp16 pair (RTZ, 1 inst)
    union { h2 h; u32 u; } v; v.h = __builtin_amdgcn_cvt_pkrtz(lo, hi); return v.u;
}
// packed fp16 relu: one v_pk_max_f16 against 0 (inline asm; ROCm 7.2 __hmax2 header is broken)
__device__ __forceinline__ u32 pkmax0(u32 x) {
    u32 r; asm("v_pk_max_f16 %0, %1, %2" : "=v"(r) : "v"(x), "v"(0u)); return r;
}
__device__ __forceinline__ u32 nrev(u32 x) {
    return ((x >> 12) & 0xFu) | ((x >> 4) & 0xF0u) | ((x << 4) & 0xF00u) | ((x << 12) & 0xF000u);
}
// compiler-level DS ordering fence: cross-lane LDS dataflow is invisible to per-lane alias
// analysis (R6 post-mortem: zb read hoisted above z1 writes -> read poison -> NaN).
// IR-level block (memory clobber) + backend scheduler block (sched_barrier). 0 runtime insts.
__device__ __forceinline__ void ds_fence() {
    asm volatile("" ::: "memory");
    __builtin_amdgcn_sched_barrier(0);
}

// ======================= prep kernel: per-LAUNCH weight transform (UNCHANGED) =======================
__launch_bounds__(256)
__global__ void smartcnn_prep(const float* __restrict__ c0w, const float* __restrict__ c0b,
                              const float* __restrict__ c1w,
                              const float* __restrict__ lw,  const float* __restrict__ ow,
                              u16* __restrict__ wsAf, u32* __restrict__ wsOw,
                              uint2* __restrict__ wsTab)
{
    const int i = blockIdx.x * 256 + threadIdx.x;
    if (i < 24576) {
        // af element: i = (T*3+s)*512 + (qd*16+m)*8 + j
        const int j    = i & 7;
        const int lane = (i >> 3) & 63;
        const int rest = i >> 9;
        const int m  = lane & 15, qd = lane >> 4;
        const int s  = rest % 3;
        const int wtt = rest / 3;
        const int tt = wtt & 3, w = wtt >> 2;
        const int tbase = ((tt & 1) ? 4 : 0) + ((tt >> 1) ? 32 : 0);
        const int fid = 64*w + tbase + 8*(m >> 2) + (m & 3);        // M-permuted feature row
        const int kp = s*32 + qd*8 + j;                              // fragment K position
        const int kq = (kp < 48) ? kp : kp - 48;                     // invert K-permutation:
        const int ko = ((kp < 48) ? 0 : 48) + (kq & 3)*12 + (kq >> 2); // kp=(ko%12)*4+ko/12
        wsAf[i] = (u16)bfr(lw[fid*96 + ko]);
    } else if (i < 26624) {
        // out_w fp16-pair element: t = (c'*64 + qd*16+m)*4 + k
        const int t = i - 24576;
        const int k    = t & 3;
        const int lane = (t >> 2) & 63;
        const int wc   = t >> 8;
        const int m = lane & 15, qd = lane >> 4;
        const int c = wc & 1, w = wc >> 1;
        u32 val = 0u;
        if (m < 4) {   // rows 0-3 = actions, rows 4-15 = 0
            const int n8 = 64*w + 32*c + qd*8;
            val = pkh(ow[m*256 + n8 + 2*k], ow[m*256 + n8 + 2*k + 1]);
        }
        wsOw[t] = val;
    } else if (i < 26866) {
        // conv pair tables: t<121 -> Th (conv0 pair + bias), else Tv (conv1 pair)
        const int t = i - 26624;
        const int e = (t < 121) ? t : t - 121;
        const int v1 = e / 11, v2 = e - v1*11;
        float a[4];
        #pragma unroll
        for (int c = 0; c < 4; ++c) {
            if (t < 121)
                a[c] = fmaxf(c0w[c*24 + 0] + c0w[c*24 + (1+v1)*2 + 0] + c0b[c]
                           + c0w[c*24 + 1] + c0w[c*24 + (1+v2)*2 + 1], 0.f);
            else
                a[c] = fmaxf(c1w[c*24 + 0] + c1w[c*24 + (1+v1)*2 + 0]
                           + c1w[c*24 + 1] + c1w[c*24 + (1+v2)*2 + 1], 0.f);
        }
        wsTab[t] = make_uint2(pk2(a[0], a[1]), pk2(a[2], a[3]));
    }
}

// ---- phase 1: flips + z1 row build + fragment read-back, wave-private rows ----
// Cross-lane redistribution through LDS: lane (qd,m) writes quadrant qd of row m; reads back
// slices written by OTHER qd lanes. HW executes same-wave DS ops in program order, but the
// COMPILER must be fenced (ds_fence) or it reorders provably-"disjoint" per-lane accesses.
__device__ __forceinline__ void phase1_fn(const int4 e4, u16* __restrict__ zrow,
                                          const uint2* __restrict__ Th, const uint2* __restrict__ Tv,
                                          const int m, const int qd,
                                          bf8& zb0, bf8& zb1, bf8& zb2, bool& fv, bool& fh)
{
    u32 pkd = (u32)e4.x | ((u32)e4.y << 4) | ((u32)e4.z << 8) | ((u32)e4.w << 12);
    u32 R0 = (u32)__shfl((int)pkd, m);
    u32 R1 = (u32)__shfl((int)pkd, m + 16);
    u32 R2 = (u32)__shfl((int)pkd, m + 32);
    u32 R3 = (u32)__shfl((int)pkd, m + 48);
    u32 c0v = R0 & 15u, c1v = (R0 >> 12) & 15u, c2v = R3 & 15u, c3v = (R3 >> 12) & 15u;
    u32 best = c0v; int ix = 0;
    if (c1v > best) { best = c1v; ix = 1; }
    if (c2v > best) { best = c2v; ix = 2; }
    if (c3v > best) { best = c3v; ix = 3; }
    fv = (ix >= 2); fh = ((ix & 1) != 0);
    u32 F0 = fv ? R3 : R0;
    u32 F1 = fv ? R2 : R1;
    u32 F2 = fv ? R1 : R2;
    u32 F3 = fv ? R0 : R3;
    if (fh) { F0 = nrev(F0); F1 = nrev(F1); F2 = nrev(F2); F3 = nrev(F3); }

    const u32 Fq = (qd == 0) ? F0 : (qd == 1) ? F1 : (qd == 2) ? F2 : F3;
    u32 nbq0 = Fq & 15u, nbq1 = (Fq >> 4) & 15u, nbq2 = (Fq >> 8) & 15u, nbq3 = (Fq >> 12) & 15u;
    u32 nbc0 = (F0 >> (4*qd)) & 15u, nbc1 = (F1 >> (4*qd)) & 15u;
    u32 nbc2 = (F2 >> (4*qd)) & 15u, nbc3 = (F3 >> (4*qd)) & 15u;

    uint2 H0 = Th[nbq0*11u + nbq1];
    uint2 H1 = Th[nbq1*11u + nbq2];
    uint2 H2 = Th[nbq2*11u + nbq3];
    uint2 V0 = Tv[nbc0*11u + nbc1];
    uint2 V1 = Tv[nbc1*11u + nbc2];
    uint2 V2 = Tv[nbc2*11u + nbc3];

    *(uint2*)(zrow + (qd*3 + 0)*4) = H0;
    *(uint2*)(zrow + (qd*3 + 1)*4) = H1;
    *(uint2*)(zrow + (qd*3 + 2)*4) = H2;
    *(uint2*)(zrow + 48 + (0*4 + qd)*4) = V0;
    *(uint2*)(zrow + 48 + (1*4 + qd)*4) = V1;
    *(uint2*)(zrow + 48 + (2*4 + qd)*4) = V2;

    ds_fence();   // RAW: all 64 lanes' writes issue before any lane's read-back

    zb0 = *(const bf8*)(zrow + qd*8);
    zb1 = *(const bf8*)(zrow + 32 + qd*8);
    zb2 = *(const bf8*)(zrow + 64 + qd*8);

    ds_fence();   // WAR: next call's writes must not hoist above these reads
}

// ======================= main kernel: barrier-free, register-budgeted =======================
// R5 post-mortem: compiler targets 128 VGPRs (ignores the LDS occupancy cap) and SPILLS if
// pressure > 128. This version is designed to ~110 peak: lb + out_w live in LDS, GEMM1 tiles
// processed in pairs and folded into GEMM2 immediately (no acc[16]), af streamed per c-block,
// 2 board-groups (32 boards) share every weight read. Zero barriers after setup.
__launch_bounds__(256, 2)
__global__ void smartcnn_fused(const int* __restrict__ exps,
                               const float* __restrict__ lb, const float* __restrict__ ob,
                               const u16* __restrict__ wsAf, const u32* __restrict__ wsOw,
                               const uint2* __restrict__ wsTab,
                               float* __restrict__ out)
{
    __shared__ u16   afL[48 * 512];      // 49152 B : all 48 W1 fragments, lane-ordered
    __shared__ uint2 ThA[121];           // conv0 pair table
    __shared__ uint2 TvA[121];           // conv1 pair table
    __shared__ f4    lbL[64];            //  1024 B : [T*4+qd] -> linear_b frag (broadcast read)
    __shared__ u32   owL[2048];          //  8192 B : out_w frags [c*256 + lane*4 + k]
    __shared__ u16   z1[64 * ZSTR];      // 13312 B : 16 rows per wave, reused per group/pass

    const int tid  = threadIdx.x;
    const int w    = tid >> 6;
    const int lane = tid & 63;
    const int m    = lane & 15;
    const int qd   = lane >> 4;

    // ---- stage tables / weights into LDS (coalesced) ----
    if (tid < 242) {
        uint2 v = wsTab[tid];
        if (tid < 121) ThA[tid] = v; else TvA[tid - 121] = v;
    }
    if (tid < 64) {
        const int T = tid >> 2, q = tid & 3;
        const int tb = ((T & 1) ? 4 : 0) + (T >> 1) * 32;
        lbL[tid] = *(const f4*)(lb + tb + 8 * q);
    }
    #pragma unroll
    for (int f2 = 0; f2 < 12; ++f2) {
        const int f = w * 12 + f2;
        uint4 t = *(const uint4*)((const char*)wsAf + f * 1024 + lane * 16);
        *(uint4*)((char*)afL + f * 1024 + lane * 16) = t;
    }
    #pragma unroll
    for (int i2 = 0; i2 < 2; ++i2) {
        const int i = i2 * 256 + tid;
        ((uint4*)owL)[i] = ((const uint4*)wsOw)[i];
    }
    const float4 obv = *(const float4*)ob;
    u16* zrow = &z1[(w*16 + m) * ZSTR];

    __syncthreads();   // the ONLY barrier

    const int wbase = blockIdx.x * 512 + w * 128;   // this wave's first board
    int4 e4a = *(const int4*)(exps + (size_t)(wbase + m)*16 + qd*4);
    int4 e4b = *(const int4*)(exps + (size_t)(wbase + 16 + m)*16 + qd*4);

    #pragma unroll 1
    for (int si = 0; si < 4; ++si) {
        // ---- phase1 both groups (z1 rows reused same-wave; zb frags land in 24 VGPRs) ----
        bf8 za0, za1, za2, zc0, zc1, zc2;
        bool fva, fha, fvb, fhb;
        phase1_fn(e4a, zrow, &ThA[0], &TvA[0], m, qd, za0, za1, za2, fva, fha);
        phase1_fn(e4b, zrow, &ThA[0], &TvA[0], m, qd, zc0, zc1, zc2, fvb, fhb);

        // prefetch next pass's boards (in flight across the whole c-loop)
        const int sn = (si < 3) ? si + 1 : si;
        e4a = *(const int4*)(exps + (size_t)(wbase + sn*32 + m)*16 + qd*4);
        e4b = *(const int4*)(exps + (size_t)(wbase + sn*32 + 16 + m)*16 + qd*4);

        // ---- fused GEMM1+GEMM2 over 8 c-blocks (tile pair 2c,2c+1 -> fold into logits) ----
        f4 pa = {0.f,0.f,0.f,0.f}, pb = {0.f,0.f,0.f,0.f};
        __builtin_amdgcn_s_setprio(1);
        #pragma unroll 1        // runtime c keeps af loads from being hoisted (R3/R5 spill trap)
        for (int c = 0; c < 8; ++c) {
            const u16* ap = &afL[c*3072 + lane*8];
            bf8 a00 = *(const bf8*)(ap);
            bf8 a01 = *(const bf8*)(ap + 512);
            bf8 a02 = *(const bf8*)(ap + 1024);
            bf8 a10 = *(const bf8*)(ap + 1536);
            bf8 a11 = *(const bf8*)(ap + 2048);
            bf8 a12 = *(const bf8*)(ap + 2560);
            f4 lb0 = lbL[c*8 + qd];
            f4 lb1 = lbL[c*8 + 4 + qd];
            union { u32 u[4]; h8 v; } au;
            uint4 owt = *(const uint4*)(&owL[c*256 + lane*4]);
            au.u[0] = owt.x; au.u[1] = owt.y; au.u[2] = owt.z; au.u[3] = owt.w;

            // group a: 2 feature tiles (K=96) -> relu/fp16 pack -> GEMM2 fold
            f4 x0 = __builtin_amdgcn_mfma_f32_16x16x32_bf16(a00, za0, lb0, 0, 0, 0);
            x0     = __builtin_amdgcn_mfma_f32_16x16x32_bf16(a01, za1, x0, 0, 0, 0);
            x0     = __builtin_amdgcn_mfma_f32_16x16x32_bf16(a02, za2, x0, 0, 0, 0);
            f4 x1 = __builtin_amdgcn_mfma_f32_16x16x32_bf16(a10, za0, lb1, 0, 0, 0);
            x1     = __builtin_amdgcn_mfma_f32_16x16x32_bf16(a11, za1, x1, 0, 0, 0);
            x1     = __builtin_amdgcn_mfma_f32_16x16x32_bf16(a12, za2, x1, 0, 0, 0);
            union { u32 u[4]; h8 v; } bu;
            bu.u[0] = pkmax0(pkh(x0[0], x0[1]));
            bu.u[1] = pkmax0(pkh(x0[2], x0[3]));
            bu.u[2] = pkmax0(pkh(x1[0], x1[1]));
            bu.u[3] = pkmax0(pkh(x1[2], x1[3]));
            pa = __builtin_amdgcn_mfma_f32_16x16x32_f16(au.v, bu.v, pa, 0, 0, 0);

            // group b: reuses a*, lb*, au (the whole point: 32 boards per weight read)
            f4 y0 = __builtin_amdgcn_mfma_f32_16x16x32_bf16(a00, zc0, lb0, 0, 0, 0);
            y0     = __builtin_amdgcn_mfma_f32_16x16x32_bf16(a01, zc1, y0, 0, 0, 0);
            y0     = __builtin_amdgcn_mfma_f32_16x16x32_bf16(a02, zc2, y0, 0, 0, 0);
            f4 y1 = __builtin_amdgcn_mfma_f32_16x16x32_bf16(a10, zc0, lb1, 0, 0, 0);
            y1     = __builtin_amdgcn_mfma_f32_16x16x32_bf16(a11, zc1, y1, 0, 0, 0);
            y1     = __builtin_amdgcn_mfma_f32_16x16x32_bf16(a12, zc2, y1, 0, 0, 0);
            bu.u[0] = pkmax0(pkh(y0[0], y0[1]));
            bu.u[1] = pkmax0(pkh(y0[2], y0[3]));
            bu.u[2] = pkmax0(pkh(y1[0], y1[1]));
            bu.u[3] = pkmax0(pkh(y1[2], y1[3]));
            pb = __builtin_amdgcn_mfma_f32_16x16x32_f16(au.v, bu.v, pb, 0, 0, 0);
        }
        __builtin_amdgcn_s_setprio(0);

        // ---- epilogue: softmax + flip-permute + store (qd==0 lanes hold the 4 action rows) ----
        if (qd == 0) {
            {
                float L0 = pa[0] + obv.x, L1 = pa[1] + obv.y, L2 = pa[2] + obv.z, L3 = pa[3] + obv.w;
                float mx = fmaxf(fmaxf(L0, L1), fmaxf(L2, L3));
                float e0 = __expf(L0-mx), e1 = __expf(L1-mx), e2 = __expf(L2-mx), e3 = __expf(L3-mx);
                float inv = __builtin_amdgcn_rcpf(e0 + e1 + e2 + e3);
                float P0 = e0*inv, P1 = e1*inv, P2 = e2*inv, P3 = e3*inv;
                float4 o;
                o.x = fva ? P1 : P0;
                o.y = fva ? P0 : P1;
                o.z = fha ? P3 : P2;
                o.w = fha ? P2 : P3;
                *(float4*)(out + (size_t)(wbase + si*32 + m) * 4) = o;
            }
            {
                float L0 = pb[0] + obv.x, L1 = pb[1] + obv.y, L2 = pb[2] + obv.z, L3 = pb[3] + obv.w;
                float mx = fmaxf(fmaxf(L0, L1), fmaxf(L2, L3));
                float e0 = __expf(L0-mx), e1 = __expf(L1-mx), e2 = __expf(L2-mx), e3 = __expf(L3-mx);
                float inv = __builtin_amdgcn_rcpf(e0 + e1 + e2 + e3);
                float P0 = e0*inv, P1 = e1*inv, P2 = e2*inv, P3 = e3*inv;
                float4 o;
                o.x = fvb ? P1 : P0;
                o.y = fvb ? P0 : P1;
                o.z = fhb ? P3 : P2;
                o.w = fhb ? P2 : P3;
                *(float4*)(out + (size_t)(wbase + si*32 + 16 + m) * 4) = o;
            }
        }
    }
}

extern "C" void kernel_launch(void* const* d_in, const int* in_sizes, int n_in,
                              void* d_out, int out_size, void* d_ws, size_t ws_size,
                              hipStream_t stream) {
    const int*   exps = (const int*)  d_in[0];
    const float* c0w  = (const float*)d_in[1];
    const float* c0b  = (const float*)d_in[2];
    const float* c1w  = (const float*)d_in[3];
    const float* lw   = (const float*)d_in[4];
    const float* lbv  = (const float*)d_in[5];
    const float* oww  = (const float*)d_in[6];
    const float* obv  = (const float*)d_in[7];
    u16*   wsAf  = (u16*)  ((char*)d_ws + WS_AF);
    u32*   wsOw  = (u32*)  ((char*)d_ws + WS_OW);
    uint2* wsTab = (uint2*)((char*)d_ws + WS_TAB);
    smartcnn_prep<<<105, 256, 0, stream>>>(c0w, c0b, c1w, lw, oww, wsAf, wsOw, wsTab);
    smartcnn_fused<<<NBLK, 256, 0, stream>>>(exps, lbv, obv, wsAf, wsOw, wsTab, (float*)d_out);
}

// Round 8
// 90.693 us; speedup vs baseline: 1.9373x; 1.0304x over previous
//
#include <hip/hip_runtime.h>

typedef unsigned int  u32;
typedef unsigned short u16;

typedef float    f4  __attribute__((ext_vector_type(4)));
typedef short    bf8 __attribute__((ext_vector_type(8)));
typedef __fp16   h8  __attribute__((ext_vector_type(8)));
typedef __fp16   h2  __attribute__((ext_vector_type(2)));

#define NBLK  256    // 256 blocks * 16 waves * 64 boards = 262144 ; 1 block per CU
#define ZSTR  104    // z1 row stride (u16); 52 dw/row; 16B-aligned rows (b128)

// ---- workspace layout (bytes); total 59280 ----
#define WS_AF   0        // u16[16*3*512]   = 49152 B : W1 bf16, K+M-permuted, lane-ordered
#define WS_OW   49152    // u32[8*64*4]     =  8192 B : out_w fp16-pair A-frags, lane-ordered
#define WS_TAB  57344    // uint2[242]      =  1936 B : Th[0..120], Tv[121..241]

// fp32 -> bf16 bits, round-half-up (weights only; ties are measure-zero)
__device__ __forceinline__ u32 bfr(float f) {
    union { float f; u32 u; } v; v.f = f;
    return (v.u + 0x8000u) >> 16;
}
__device__ __forceinline__ u32 pk2(float lo, float hi) { return bfr(lo) | (bfr(hi) << 16); }
__device__ __forceinline__ u32 pkh(float lo, float hi) {   // fp16 pair (RTZ, 1 inst)
    union { h2 h; u32 u; } v; v.h = __builtin_amdgcn_cvt_pkrtz(lo, hi); return v.u;
}
// packed fp16 relu: one v_pk_max_f16 against 0 (inline asm; ROCm 7.2 __hmax2 header is broken)
__device__ __forceinline__ u32 pkmax0(u32 x) {
    u32 r; asm("v_pk_max_f16 %0, %1, %2" : "=v"(r) : "v"(x), "v"(0u)); return r;
}
__device__ __forceinline__ u32 nrev(u32 x) {
    return ((x >> 12) & 0xFu) | ((x >> 4) & 0xF0u) | ((x << 4) & 0xF00u) | ((x << 12) & 0xF000u);
}
// compiler-level DS ordering fence: cross-lane LDS dataflow is invisible to per-lane alias
// analysis (R6 post-mortem: zb read hoisted above z1 writes -> read poison -> NaN).
__device__ __forceinline__ void ds_fence() {
    asm volatile("" ::: "memory");
    __builtin_amdgcn_sched_barrier(0);
}

// ======================= prep kernel: per-LAUNCH weight transform (UNCHANGED) =======================
__launch_bounds__(256)
__global__ void smartcnn_prep(const float* __restrict__ c0w, const float* __restrict__ c0b,
                              const float* __restrict__ c1w,
                              const float* __restrict__ lw,  const float* __restrict__ ow,
                              u16* __restrict__ wsAf, u32* __restrict__ wsOw,
                              uint2* __restrict__ wsTab)
{
    const int i = blockIdx.x * 256 + threadIdx.x;
    if (i < 24576) {
        // af element: i = (T*3+s)*512 + (qd*16+m)*8 + j
        const int j    = i & 7;
        const int lane = (i >> 3) & 63;
        const int rest = i >> 9;
        const int m  = lane & 15, qd = lane >> 4;
        const int s  = rest % 3;
        const int wtt = rest / 3;
        const int tt = wtt & 3, w = wtt >> 2;
        const int tbase = ((tt & 1) ? 4 : 0) + ((tt >> 1) ? 32 : 0);
        const int fid = 64*w + tbase + 8*(m >> 2) + (m & 3);        // M-permuted feature row
        const int kp = s*32 + qd*8 + j;                              // fragment K position
        const int kq = (kp < 48) ? kp : kp - 48;                     // invert K-permutation:
        const int ko = ((kp < 48) ? 0 : 48) + (kq & 3)*12 + (kq >> 2); // kp=(ko%12)*4+ko/12
        wsAf[i] = (u16)bfr(lw[fid*96 + ko]);
    } else if (i < 26624) {
        // out_w fp16-pair element: t = (c'*64 + qd*16+m)*4 + k
        const int t = i - 24576;
        const int k    = t & 3;
        const int lane = (t >> 2) & 63;
        const int wc   = t >> 8;
        const int m = lane & 15, qd = lane >> 4;
        const int c = wc & 1, w = wc >> 1;
        u32 val = 0u;
        if (m < 4) {   // rows 0-3 = actions, rows 4-15 = 0
            const int n8 = 64*w + 32*c + qd*8;
            val = pkh(ow[m*256 + n8 + 2*k], ow[m*256 + n8 + 2*k + 1]);
        }
        wsOw[t] = val;
    } else if (i < 26866) {
        // conv pair tables: t<121 -> Th (conv0 pair + bias), else Tv (conv1 pair)
        const int t = i - 26624;
        const int e = (t < 121) ? t : t - 121;
        const int v1 = e / 11, v2 = e - v1*11;
        float a[4];
        #pragma unroll
        for (int c = 0; c < 4; ++c) {
            if (t < 121)
                a[c] = fmaxf(c0w[c*24 + 0] + c0w[c*24 + (1+v1)*2 + 0] + c0b[c]
                           + c0w[c*24 + 1] + c0w[c*24 + (1+v2)*2 + 1], 0.f);
            else
                a[c] = fmaxf(c1w[c*24 + 0] + c1w[c*24 + (1+v1)*2 + 0]
                           + c1w[c*24 + 1] + c1w[c*24 + (1+v2)*2 + 1], 0.f);
        }
        wsTab[t] = make_uint2(pk2(a[0], a[1]), pk2(a[2], a[3]));
    }
}

// ---- phase 1: flips + z1 row build + fragment read-back, wave-private rows ----
__device__ __forceinline__ void phase1_fn(const int4 e4, u16* __restrict__ zrow,
                                          const uint2* __restrict__ Th, const uint2* __restrict__ Tv,
                                          const int m, const int qd,
                                          bf8& zb0, bf8& zb1, bf8& zb2, bool& fv, bool& fh)
{
    u32 pkd = (u32)e4.x | ((u32)e4.y << 4) | ((u32)e4.z << 8) | ((u32)e4.w << 12);
    u32 R0 = (u32)__shfl((int)pkd, m);
    u32 R1 = (u32)__shfl((int)pkd, m + 16);
    u32 R2 = (u32)__shfl((int)pkd, m + 32);
    u32 R3 = (u32)__shfl((int)pkd, m + 48);
    u32 c0v = R0 & 15u, c1v = (R0 >> 12) & 15u, c2v = R3 & 15u, c3v = (R3 >> 12) & 15u;
    u32 best = c0v; int ix = 0;
    if (c1v > best) { best = c1v; ix = 1; }
    if (c2v > best) { best = c2v; ix = 2; }
    if (c3v > best) { best = c3v; ix = 3; }
    fv = (ix >= 2); fh = ((ix & 1) != 0);
    u32 F0 = fv ? R3 : R0;
    u32 F1 = fv ? R2 : R1;
    u32 F2 = fv ? R1 : R2;
    u32 F3 = fv ? R0 : R3;
    if (fh) { F0 = nrev(F0); F1 = nrev(F1); F2 = nrev(F2); F3 = nrev(F3); }

    const u32 Fq = (qd == 0) ? F0 : (qd == 1) ? F1 : (qd == 2) ? F2 : F3;
    u32 nbq0 = Fq & 15u, nbq1 = (Fq >> 4) & 15u, nbq2 = (Fq >> 8) & 15u, nbq3 = (Fq >> 12) & 15u;
    u32 nbc0 = (F0 >> (4*qd)) & 15u, nbc1 = (F1 >> (4*qd)) & 15u;
    u32 nbc2 = (F2 >> (4*qd)) & 15u, nbc3 = (F3 >> (4*qd)) & 15u;

    uint2 H0 = Th[nbq0*11u + nbq1];
    uint2 H1 = Th[nbq1*11u + nbq2];
    uint2 H2 = Th[nbq2*11u + nbq3];
    uint2 V0 = Tv[nbc0*11u + nbc1];
    uint2 V1 = Tv[nbc1*11u + nbc2];
    uint2 V2 = Tv[nbc2*11u + nbc3];

    *(uint2*)(zrow + (qd*3 + 0)*4) = H0;
    *(uint2*)(zrow + (qd*3 + 1)*4) = H1;
    *(uint2*)(zrow + (qd*3 + 2)*4) = H2;
    *(uint2*)(zrow + 48 + (0*4 + qd)*4) = V0;
    *(uint2*)(zrow + 48 + (1*4 + qd)*4) = V1;
    *(uint2*)(zrow + 48 + (2*4 + qd)*4) = V2;

    ds_fence();   // RAW: all 64 lanes' writes issue before any lane's read-back

    zb0 = *(const bf8*)(zrow + qd*8);
    zb1 = *(const bf8*)(zrow + 32 + qd*8);
    zb2 = *(const bf8*)(zrow + 64 + qd*8);

    ds_fence();   // WAR: next call's writes must not hoist above these reads
}

// ======================= main kernel: barrier-free, CU-sized block (4 waves/SIMD) =======================
// R7 post-mortem: barrier-free @ 2 waves/SIMD == barriered @ 4 waves/SIMD == ~40us: both are
// latency-bound ~3x above the ~13us LDS-pipe floor. This round: ONE 1024-thread block per CU ->
// 16 waves share a single afL copy; LDS 113.6KB < 160KB -> 16 waves/CU = 4 waves/SIMD, barrier-free.
// Same inner loop as R7 (single-variable test of the TLP theory). VGPR cap 128 (= R5/R7 de-facto target).
__launch_bounds__(1024, 4)
__global__ void smartcnn_fused(const int* __restrict__ exps,
                               const float* __restrict__ lb, const float* __restrict__ ob,
                               const u16* __restrict__ wsAf, const u32* __restrict__ wsOw,
                               const uint2* __restrict__ wsTab,
                               float* __restrict__ out)
{
    __shared__ u16   afL[48 * 512];      // 49152 B : all 48 W1 fragments (ONE copy per CU)
    __shared__ uint2 ThA[121];           // conv0 pair table
    __shared__ uint2 TvA[121];           // conv1 pair table
    __shared__ f4    lbL[64];            //  1024 B : [T*4+qd] -> linear_b frag (broadcast read)
    __shared__ u32   owL[2048];          //  8192 B : out_w frags [c*256 + lane*4 + k]
    __shared__ u16   z1[256 * ZSTR];     // 53248 B : 16 rows per wave x 16 waves

    const int tid  = threadIdx.x;
    const int w    = tid >> 6;           // wave id 0..15
    const int lane = tid & 63;
    const int m    = lane & 15;
    const int qd   = lane >> 4;

    // ---- stage tables / weights into LDS (coalesced, 1024 threads) ----
    if (tid < 242) {
        uint2 v = wsTab[tid];
        if (tid < 121) ThA[tid] = v; else TvA[tid - 121] = v;
    }
    if (tid < 64) {
        const int T = tid >> 2, q = tid & 3;
        const int tb = ((T & 1) ? 4 : 0) + (T >> 1) * 32;
        lbL[tid] = *(const f4*)(lb + tb + 8 * q);
    }
    #pragma unroll
    for (int k = 0; k < 3; ++k) {        // 3072 uint4 total
        const int i = k * 1024 + tid;
        ((uint4*)afL)[i] = ((const uint4*)wsAf)[i];
    }
    if (tid < 512)                       // 512 uint4 total
        ((uint4*)owL)[tid] = ((const uint4*)wsOw)[tid];
    const float4 obv = *(const float4*)ob;
    u16* zrow = &z1[(w*16 + m) * ZSTR];

    __syncthreads();   // the ONLY barrier (setup publish)

    const int wbase = blockIdx.x * 1024 + w * 64;   // this wave's first board (64 boards/wave)
    int4 e4a = *(const int4*)(exps + (size_t)(wbase + m)*16 + qd*4);
    int4 e4b = *(const int4*)(exps + (size_t)(wbase + 16 + m)*16 + qd*4);

    #pragma unroll 1
    for (int si = 0; si < 2; ++si) {
        // ---- phase1 both groups (z1 rows reused same-wave; zb frags land in 24 VGPRs) ----
        bf8 za0, za1, za2, zc0, zc1, zc2;
        bool fva, fha, fvb, fhb;
        phase1_fn(e4a, zrow, &ThA[0], &TvA[0], m, qd, za0, za1, za2, fva, fha);
        phase1_fn(e4b, zrow, &ThA[0], &TvA[0], m, qd, zc0, zc1, zc2, fvb, fhb);

        // prefetch next pass's boards (in flight across the whole c-loop)
        const int sn = (si < 1) ? si + 1 : si;
        e4a = *(const int4*)(exps + (size_t)(wbase + sn*32 + m)*16 + qd*4);
        e4b = *(const int4*)(exps + (size_t)(wbase + sn*32 + 16 + m)*16 + qd*4);

        // ---- fused GEMM1+GEMM2 over 8 c-blocks (tile pair 2c,2c+1 -> fold into logits) ----
        f4 pa = {0.f,0.f,0.f,0.f}, pb = {0.f,0.f,0.f,0.f};
        __builtin_amdgcn_s_setprio(1);
        #pragma unroll 1        // runtime c keeps af loads from being hoisted (R3/R5 spill trap)
        for (int c = 0; c < 8; ++c) {
            const u16* ap = &afL[c*3072 + lane*8];
            bf8 a00 = *(const bf8*)(ap);
            bf8 a01 = *(const bf8*)(ap + 512);
            bf8 a02 = *(const bf8*)(ap + 1024);
            bf8 a10 = *(const bf8*)(ap + 1536);
            bf8 a11 = *(const bf8*)(ap + 2048);
            bf8 a12 = *(const bf8*)(ap + 2560);
            f4 lb0 = lbL[c*8 + qd];
            f4 lb1 = lbL[c*8 + 4 + qd];
            union { u32 u[4]; h8 v; } au;
            uint4 owt = *(const uint4*)(&owL[c*256 + lane*4]);
            au.u[0] = owt.x; au.u[1] = owt.y; au.u[2] = owt.z; au.u[3] = owt.w;

            // group a: 2 feature tiles (K=96) -> relu/fp16 pack -> GEMM2 fold
            f4 x0 = __builtin_amdgcn_mfma_f32_16x16x32_bf16(a00, za0, lb0, 0, 0, 0);
            x0     = __builtin_amdgcn_mfma_f32_16x16x32_bf16(a01, za1, x0, 0, 0, 0);
            x0     = __builtin_amdgcn_mfma_f32_16x16x32_bf16(a02, za2, x0, 0, 0, 0);
            f4 x1 = __builtin_amdgcn_mfma_f32_16x16x32_bf16(a10, za0, lb1, 0, 0, 0);
            x1     = __builtin_amdgcn_mfma_f32_16x16x32_bf16(a11, za1, x1, 0, 0, 0);
            x1     = __builtin_amdgcn_mfma_f32_16x16x32_bf16(a12, za2, x1, 0, 0, 0);
            union { u32 u[4]; h8 v; } bu;
            bu.u[0] = pkmax0(pkh(x0[0], x0[1]));
            bu.u[1] = pkmax0(pkh(x0[2], x0[3]));
            bu.u[2] = pkmax0(pkh(x1[0], x1[1]));
            bu.u[3] = pkmax0(pkh(x1[2], x1[3]));
            pa = __builtin_amdgcn_mfma_f32_16x16x32_f16(au.v, bu.v, pa, 0, 0, 0);

            // group b: reuses a*, lb*, au (32 boards per weight read)
            f4 y0 = __builtin_amdgcn_mfma_f32_16x16x32_bf16(a00, zc0, lb0, 0, 0, 0);
            y0     = __builtin_amdgcn_mfma_f32_16x16x32_bf16(a01, zc1, y0, 0, 0, 0);
            y0     = __builtin_amdgcn_mfma_f32_16x16x32_bf16(a02, zc2, y0, 0, 0, 0);
            f4 y1 = __builtin_amdgcn_mfma_f32_16x16x32_bf16(a10, zc0, lb1, 0, 0, 0);
            y1     = __builtin_amdgcn_mfma_f32_16x16x32_bf16(a11, zc1, y1, 0, 0, 0);
            y1     = __builtin_amdgcn_mfma_f32_16x16x32_bf16(a12, zc2, y1, 0, 0, 0);
            bu.u[0] = pkmax0(pkh(y0[0], y0[1]));
            bu.u[1] = pkmax0(pkh(y0[2], y0[3]));
            bu.u[2] = pkmax0(pkh(y1[0], y1[1]));
            bu.u[3] = pkmax0(pkh(y1[2], y1[3]));
            pb = __builtin_amdgcn_mfma_f32_16x16x32_f16(au.v, bu.v, pb, 0, 0, 0);
        }
        __builtin_amdgcn_s_setprio(0);

        // ---- epilogue: softmax + flip-permute + store (qd==0 lanes hold the 4 action rows) ----
        if (qd == 0) {
            {
                float L0 = pa[0] + obv.x, L1 = pa[1] + obv.y, L2 = pa[2] + obv.z, L3 = pa[3] + obv.w;
                float mx = fmaxf(fmaxf(L0, L1), fmaxf(L2, L3));
                float e0 = __expf(L0-mx), e1 = __expf(L1-mx), e2 = __expf(L2-mx), e3 = __expf(L3-mx);
                float inv = __builtin_amdgcn_rcpf(e0 + e1 + e2 + e3);
                float P0 = e0*inv, P1 = e1*inv, P2 = e2*inv, P3 = e3*inv;
                float4 o;
                o.x = fva ? P1 : P0;
                o.y = fva ? P0 : P1;
                o.z = fha ? P3 : P2;
                o.w = fha ? P2 : P3;
                *(float4*)(out + (size_t)(wbase + si*32 + m) * 4) = o;
            }
            {
                float L0 = pb[0] + obv.x, L1 = pb[1] + obv.y, L2 = pb[2] + obv.z, L3 = pb[3] + obv.w;
                float mx = fmaxf(fmaxf(L0, L1), fmaxf(L2, L3));
                float e0 = __expf(L0-mx), e1 = __expf(L1-mx), e2 = __expf(L2-mx), e3 = __expf(L3-mx);
                float inv = __builtin_amdgcn_rcpf(e0 + e1 + e2 + e3);
                float P0 = e0*inv, P1 = e1*inv, P2 = e2*inv, P3 = e3*inv;
                float4 o;
                o.x = fvb ? P1 : P0;
                o.y = fvb ? P0 : P1;
                o.z = fhb ? P3 : P2;
                o.w = fhb ? P2 : P3;
                *(float4*)(out + (size_t)(wbase + si*32 + 16 + m) * 4) = o;
            }
        }
    }
}

extern "C" void kernel_launch(void* const* d_in, const int* in_sizes, int n_in,
                              void* d_out, int out_size, void* d_ws, size_t ws_size,
                              hipStream_t stream) {
    const int*   exps = (const int*)  d_in[0];
    const float* c0w  = (const float*)d_in[1];
    const float* c0b  = (const float*)d_in[2];
    const float* c1w  = (const float*)d_in[3];
    const float* lw   = (const float*)d_in[4];
    const float* lbv  = (const float*)d_in[5];
    const float* oww  = (const float*)d_in[6];
    const float* obv  = (const float*)d_in[7];
    u16*   wsAf  = (u16*)  ((char*)d_ws + WS_AF);
    u32*   wsOw  = (u32*)  ((char*)d_ws + WS_OW);
    uint2* wsTab = (uint2*)((char*)d_ws + WS_TAB);
    smartcnn_prep<<<105, 256, 0, stream>>>(c0w, c0b, c1w, lw, oww, wsAf, wsOw, wsTab);
    smartcnn_fused<<<NBLK, 1024, 0, stream>>>(exps, lbv, obv, wsAf, wsOw, wsTab, (float*)d_out);
}